// Round 1
// baseline (1545.229 us; speedup 1.0000x reference)
//
#include <hip/hip_runtime.h>
#include <hip/hip_bf16.h>
#include <cstdint>
#include <cstddef>

// Problem constants (B,T,H,W,D)=(2,8,16,16,2048), E=16, I=2048
#define NTOK 4096   // N = B*T*H*W
#define NEXP 16     // E
#define DIM  2048   // D
#define IDIM 2048   // I
#define CAP  640    // 2 * ceil(N/E * 1.25)
#define SEQ  2048   // T*H*W
// token n <-> memory row (n&1)*SEQ + (n>>1)   (B=2)

typedef float v4f __attribute__((ext_vector_type(4)));
typedef short v8s __attribute__((ext_vector_type(8)));

__device__ __forceinline__ unsigned short f2b(float x) {
    union { float f; unsigned u; } c; c.f = x;
    unsigned r = c.u + 0x7FFFu + ((c.u >> 16) & 1u);
    return (unsigned short)(r >> 16);
}
__device__ __forceinline__ float b2f(unsigned short x) {
    union { unsigned u; float f; } c; c.u = ((unsigned)x) << 16;
    return c.f;
}

// ---------------- Kernel 1: router (fp32 exact) ----------------
// one wave per token: lane = expert(e=lane&15) x chunk(lane>>4, 4 chunks of 512)
__global__ __launch_bounds__(256) void router_kernel(
    const float* __restrict__ hidden, const float* __restrict__ wg,
    int* __restrict__ top1, int* __restrict__ top2,
    float* __restrict__ w1, float* __restrict__ w2)
{
    int wid  = threadIdx.x >> 6;
    int lane = threadIdx.x & 63;
    int n = blockIdx.x * 4 + wid;
    int e = lane & 15;
    int chunk = lane >> 4;
    const float* tok  = hidden + ((size_t)(n & 1) * SEQ + (n >> 1)) * DIM;
    const float* wrow = wg + (size_t)e * DIM;
    float acc = 0.f;
    int d0 = chunk * (DIM / 4);
    #pragma unroll 4
    for (int d = d0; d < d0 + DIM / 4; d += 4) {
        float4 t4 = *(const float4*)(tok + d);
        float4 g4 = *(const float4*)(wrow + d);
        acc += t4.x * g4.x + t4.y * g4.y + t4.z * g4.z + t4.w * g4.w;
    }
    acc += __shfl_down(acc, 32);
    acc += __shfl_down(acc, 16);
    // lanes 0..15 hold the 16 logits
    float v = acc;
    float v1 = v; int i1 = e;
    #pragma unroll
    for (int off = 8; off; off >>= 1) {
        float ov = __shfl_xor(v1, off);
        int   oi = __shfl_xor(i1, off);
        if (ov > v1 || (ov == v1 && oi < i1)) { v1 = ov; i1 = oi; }
    }
    float v2 = (e == i1) ? -INFINITY : v; int i2 = e;
    #pragma unroll
    for (int off = 8; off; off >>= 1) {
        float ov = __shfl_xor(v2, off);
        int   oi = __shfl_xor(i2, off);
        if (ov > v2 || (ov == v2 && oi < i2)) { v2 = ov; i2 = oi; }
    }
    if (lane == 0) {
        // w1 = softmax1/(softmax1+softmax2) = 1/(1+exp(l2-l1)) (denominator cancels)
        float e2v = expf(v2 - v1);
        float inv = 1.f / (1.f + e2v);
        top1[n] = i1; top2[n] = i2;
        w1[n] = inv;  w2[n] = e2v * inv;
    }
}

// ---------------- Kernel 2: slot scan (one wave per expert) ----------------
// order matches ref cumsum: all k=0 assignments (token order), then all k=1
__global__ __launch_bounds__(1024) void slot_kernel(
    const int* __restrict__ top1, const int* __restrict__ top2,
    int* __restrict__ slot1, int* __restrict__ slot2,
    int* __restrict__ exp_tok, int* __restrict__ counts)
{
    int w = threadIdx.x >> 6;   // expert id
    int lane = threadIdx.x & 63;
    unsigned long long below = (lane == 63) ? ~0ull >> 1 : ((1ull << (lane + 1)) - 1) >> 1;
    // below = mask of lanes strictly less than `lane`
    below = (lane == 0) ? 0ull : ((~0ull) >> (64 - lane));
    int base = 0;
    for (int c = 0; c < NTOK / 64; ++c) {
        int n = c * 64 + lane;
        bool p = (top1[n] == w);
        unsigned long long m = __ballot(p);
        if (p) {
            int s = base + __popcll(m & below);
            slot1[n] = s;
            if (s < CAP) exp_tok[w * CAP + s] = n;
        }
        base += __popcll(m);
    }
    for (int c = 0; c < NTOK / 64; ++c) {
        int n = c * 64 + lane;
        bool p = (top2[n] == w);
        unsigned long long m = __ballot(p);
        if (p) {
            int s = base + __popcll(m & below);
            slot2[n] = s;
            if (s < CAP) exp_tok[w * CAP + s] = n;
        }
        base += __popcll(m);
    }
    if (lane == 0) counts[w] = base < CAP ? base : CAP;
}

// ---------------- Kernel 3: dispatch/gather -> (E,C,D) bf16 ----------------
__global__ __launch_bounds__(256) void dispatch_kernel(
    const float* __restrict__ hidden, const int* __restrict__ exp_tok,
    const int* __restrict__ counts, unsigned short* __restrict__ disp)
{
    int s = blockIdx.x, e = blockIdx.y;
    unsigned short* dst = disp + ((size_t)e * CAP + s) * DIM + threadIdx.x * 8;
    if (s < counts[e]) {
        int n = exp_tok[e * CAP + s];
        const float* src = hidden + ((size_t)(n & 1) * SEQ + (n >> 1)) * DIM + threadIdx.x * 8;
        float4 a = *(const float4*)src;
        float4 b = *(const float4*)(src + 4);
        v8s o;
        o[0] = (short)f2b(a.x); o[1] = (short)f2b(a.y);
        o[2] = (short)f2b(a.z); o[3] = (short)f2b(a.w);
        o[4] = (short)f2b(b.x); o[5] = (short)f2b(b.y);
        o[6] = (short)f2b(b.z); o[7] = (short)f2b(b.w);
        *(v8s*)dst = o;
    } else {
        v8s z = {0, 0, 0, 0, 0, 0, 0, 0};
        *(v8s*)dst = z;
    }
}

// ---------------- GEMM tiling ----------------
#define BM 128
#define BN 128
#define BK 64
#define LDT 72   // BK + 8 pad (bf16 elems): keeps 16B alignment, 2-way conflicts only

// Kernel 4: h = silu(disp @ gp^T) * (disp @ up^T), per expert. Out bf16 (E,C,I)
__global__ __launch_bounds__(256) void gateup_kernel(
    const unsigned short* __restrict__ disp, const float* __restrict__ gp,
    const float* __restrict__ up, unsigned short* __restrict__ hbuf)
{
    __shared__ unsigned short As[BM * LDT];
    __shared__ unsigned short Bgs[BN * LDT];
    __shared__ unsigned short Bus[BN * LDT];
    int e  = blockIdx.z;
    int m0 = blockIdx.x * BM;
    int n0 = blockIdx.y * BN;
    int tid = threadIdx.x;
    int wid = tid >> 6, lane = tid & 63;
    int wm = wid & 1, wn = wid >> 1;
    int lrow = lane & 15, quad = lane >> 4;

    const unsigned short* Ab = disp + (size_t)e * CAP * DIM;
    const float* Gb = gp + (size_t)e * IDIM * DIM;
    const float* Ub = up + (size_t)e * IDIM * DIM;

    int r = tid >> 1, h = tid & 1;   // staging: 2 threads per row, 32 elems each

    v4f accg[4][4], accu[4][4];
    #pragma unroll
    for (int i = 0; i < 4; ++i)
        #pragma unroll
        for (int j = 0; j < 4; ++j) { accg[i][j] = (v4f)0.f; accu[i][j] = (v4f)0.f; }

    for (int k0 = 0; k0 < DIM; k0 += BK) {
        { // A (already bf16)
            const unsigned short* g = Ab + (size_t)(m0 + r) * DIM + k0 + h * 32;
            unsigned short* d = As + r * LDT + h * 32;
            #pragma unroll
            for (int q = 0; q < 4; ++q)
                *(v8s*)(d + q * 8) = *(const v8s*)(g + q * 8);
        }
        { // gate weights fp32 -> bf16
            const float* g = Gb + (size_t)(n0 + r) * DIM + k0 + h * 32;
            unsigned short* d = Bgs + r * LDT + h * 32;
            #pragma unroll
            for (int q = 0; q < 4; ++q) {
                float4 f0 = *(const float4*)(g + q * 8);
                float4 f1 = *(const float4*)(g + q * 8 + 4);
                v8s o;
                o[0]=(short)f2b(f0.x); o[1]=(short)f2b(f0.y); o[2]=(short)f2b(f0.z); o[3]=(short)f2b(f0.w);
                o[4]=(short)f2b(f1.x); o[5]=(short)f2b(f1.y); o[6]=(short)f2b(f1.z); o[7]=(short)f2b(f1.w);
                *(v8s*)(d + q * 8) = o;
            }
        }
        { // up weights fp32 -> bf16
            const float* g = Ub + (size_t)(n0 + r) * DIM + k0 + h * 32;
            unsigned short* d = Bus + r * LDT + h * 32;
            #pragma unroll
            for (int q = 0; q < 4; ++q) {
                float4 f0 = *(const float4*)(g + q * 8);
                float4 f1 = *(const float4*)(g + q * 8 + 4);
                v8s o;
                o[0]=(short)f2b(f0.x); o[1]=(short)f2b(f0.y); o[2]=(short)f2b(f0.z); o[3]=(short)f2b(f0.w);
                o[4]=(short)f2b(f1.x); o[5]=(short)f2b(f1.y); o[6]=(short)f2b(f1.z); o[7]=(short)f2b(f1.w);
                *(v8s*)(d + q * 8) = o;
            }
        }
        __syncthreads();
        #pragma unroll
        for (int ks = 0; ks < BK; ks += 32) {
            v8s a[4], bg[4], bu[4];
            #pragma unroll
            for (int i = 0; i < 4; ++i)
                a[i] = *(const v8s*)&As[(wm * 64 + i * 16 + lrow) * LDT + ks + quad * 8];
            #pragma unroll
            for (int j = 0; j < 4; ++j) {
                bg[j] = *(const v8s*)&Bgs[(wn * 64 + j * 16 + lrow) * LDT + ks + quad * 8];
                bu[j] = *(const v8s*)&Bus[(wn * 64 + j * 16 + lrow) * LDT + ks + quad * 8];
            }
            #pragma unroll
            for (int i = 0; i < 4; ++i)
                #pragma unroll
                for (int j = 0; j < 4; ++j) {
                    accg[i][j] = __builtin_amdgcn_mfma_f32_16x16x32_bf16(a[i], bg[j], accg[i][j], 0, 0, 0);
                    accu[i][j] = __builtin_amdgcn_mfma_f32_16x16x32_bf16(a[i], bu[j], accu[i][j], 0, 0, 0);
                }
        }
        __syncthreads();
    }
    // epilogue: h = silu(g)*u, bf16
    unsigned short* hb = hbuf + (size_t)e * CAP * IDIM;
    #pragma unroll
    for (int i = 0; i < 4; ++i)
        #pragma unroll
        for (int j = 0; j < 4; ++j) {
            int row = m0 + wm * 64 + i * 16 + quad * 4;
            int col = n0 + wn * 64 + j * 16 + lrow;
            #pragma unroll
            for (int rg = 0; rg < 4; ++rg) {
                float g = accg[i][j][rg], u = accu[i][j][rg];
                float hv = (g / (1.f + __expf(-g))) * u;
                hb[(size_t)(row + rg) * IDIM + col] = f2b(hv);
            }
        }
}

// Kernel 5: expert_out = h @ dp^T per expert. Out bf16 (E,C,D)
__global__ __launch_bounds__(256) void down_kernel(
    const unsigned short* __restrict__ hbuf, const float* __restrict__ dp,
    unsigned short* __restrict__ eo)
{
    __shared__ unsigned short As[BM * LDT];
    __shared__ unsigned short Bs[BN * LDT];
    int e  = blockIdx.z;
    int m0 = blockIdx.x * BM;
    int n0 = blockIdx.y * BN;
    int tid = threadIdx.x;
    int wid = tid >> 6, lane = tid & 63;
    int wm = wid & 1, wn = wid >> 1;
    int lrow = lane & 15, quad = lane >> 4;

    const unsigned short* Ab = hbuf + (size_t)e * CAP * IDIM;
    const float* Db = dp + (size_t)e * DIM * IDIM;
    int r = tid >> 1, h = tid & 1;

    v4f acc[4][4];
    #pragma unroll
    for (int i = 0; i < 4; ++i)
        #pragma unroll
        for (int j = 0; j < 4; ++j) acc[i][j] = (v4f)0.f;

    for (int k0 = 0; k0 < IDIM; k0 += BK) {
        {
            const unsigned short* g = Ab + (size_t)(m0 + r) * IDIM + k0 + h * 32;
            unsigned short* d = As + r * LDT + h * 32;
            #pragma unroll
            for (int q = 0; q < 4; ++q)
                *(v8s*)(d + q * 8) = *(const v8s*)(g + q * 8);
        }
        {
            const float* g = Db + (size_t)(n0 + r) * IDIM + k0 + h * 32;
            unsigned short* d = Bs + r * LDT + h * 32;
            #pragma unroll
            for (int q = 0; q < 4; ++q) {
                float4 f0 = *(const float4*)(g + q * 8);
                float4 f1 = *(const float4*)(g + q * 8 + 4);
                v8s o;
                o[0]=(short)f2b(f0.x); o[1]=(short)f2b(f0.y); o[2]=(short)f2b(f0.z); o[3]=(short)f2b(f0.w);
                o[4]=(short)f2b(f1.x); o[5]=(short)f2b(f1.y); o[6]=(short)f2b(f1.z); o[7]=(short)f2b(f1.w);
                *(v8s*)(d + q * 8) = o;
            }
        }
        __syncthreads();
        #pragma unroll
        for (int ks = 0; ks < BK; ks += 32) {
            v8s a[4], b[4];
            #pragma unroll
            for (int i = 0; i < 4; ++i)
                a[i] = *(const v8s*)&As[(wm * 64 + i * 16 + lrow) * LDT + ks + quad * 8];
            #pragma unroll
            for (int j = 0; j < 4; ++j)
                b[j] = *(const v8s*)&Bs[(wn * 64 + j * 16 + lrow) * LDT + ks + quad * 8];
            #pragma unroll
            for (int i = 0; i < 4; ++i)
                #pragma unroll
                for (int j = 0; j < 4; ++j)
                    acc[i][j] = __builtin_amdgcn_mfma_f32_16x16x32_bf16(a[i], b[j], acc[i][j], 0, 0, 0);
        }
        __syncthreads();
    }
    unsigned short* ob = eo + (size_t)e * CAP * DIM;
    #pragma unroll
    for (int i = 0; i < 4; ++i)
        #pragma unroll
        for (int j = 0; j < 4; ++j) {
            int row = m0 + wm * 64 + i * 16 + quad * 4;
            int col = n0 + wn * 64 + j * 16 + lrow;
            #pragma unroll
            for (int rg = 0; rg < 4; ++rg)
                ob[(size_t)(row + rg) * DIM + col] = f2b(acc[i][j][rg]);
        }
}

// ---------------- Kernel 6: combine ----------------
__global__ __launch_bounds__(256) void combine_kernel(
    const unsigned short* __restrict__ eo,
    const int* __restrict__ top1, const int* __restrict__ top2,
    const int* __restrict__ slot1, const int* __restrict__ slot2,
    const float* __restrict__ w1, const float* __restrict__ w2,
    float* __restrict__ out)
{
    int n = blockIdx.x;
    int d = threadIdx.x * 8;
    float acc[8];
    #pragma unroll
    for (int i = 0; i < 8; ++i) acc[i] = 0.f;
    int s1 = slot1[n], s2 = slot2[n];
    if (s1 < CAP) {
        const unsigned short* p = eo + ((size_t)top1[n] * CAP + s1) * DIM + d;
        float w = w1[n];
        v8s v = *(const v8s*)p;
        #pragma unroll
        for (int i = 0; i < 8; ++i) acc[i] += w * b2f((unsigned short)v[i]);
    }
    if (s2 < CAP) {
        const unsigned short* p = eo + ((size_t)top2[n] * CAP + s2) * DIM + d;
        float w = w2[n];
        v8s v = *(const v8s*)p;
        #pragma unroll
        for (int i = 0; i < 8; ++i) acc[i] += w * b2f((unsigned short)v[i]);
    }
    float* o = out + ((size_t)(n & 1) * SEQ + (n >> 1)) * DIM + d;
    float4 o0 = {acc[0], acc[1], acc[2], acc[3]};
    float4 o1 = {acc[4], acc[5], acc[6], acc[7]};
    *(float4*)o = o0;
    *(float4*)(o + 4) = o1;
}

extern "C" void kernel_launch(void* const* d_in, const int* in_sizes, int n_in,
                              void* d_out, int out_size, void* d_ws, size_t ws_size,
                              hipStream_t stream) {
    const float* hidden = (const float*)d_in[0];
    const float* wg     = (const float*)d_in[1];
    const float* gp     = (const float*)d_in[2];
    const float* up     = (const float*)d_in[3];
    const float* dp     = (const float*)d_in[4];
    float* out = (float*)d_out;
    char* ws = (char*)d_ws;

    // workspace layout (all 256B-aligned)
    int*   top1    = (int*)(ws + 0);
    int*   top2    = (int*)(ws + 16384);
    float* w1      = (float*)(ws + 32768);
    float* w2      = (float*)(ws + 49152);
    int*   slot1   = (int*)(ws + 65536);
    int*   slot2   = (int*)(ws + 81920);
    int*   counts  = (int*)(ws + 98304);
    int*   exp_tok = (int*)(ws + 98560);
    unsigned short* disp = (unsigned short*)(ws + 139520);                 // 41,943,040 B
    unsigned short* hbuf = (unsigned short*)(ws + 139520 + 41943040ull);   // 41,943,040 B
    unsigned short* eo   = (unsigned short*)(ws + 139520 + 2ull * 41943040ull);

    router_kernel<<<NTOK / 4, 256, 0, stream>>>(hidden, wg, top1, top2, w1, w2);
    slot_kernel<<<1, 1024, 0, stream>>>(top1, top2, slot1, slot2, exp_tok, counts);
    dispatch_kernel<<<dim3(CAP, NEXP), 256, 0, stream>>>(hidden, exp_tok, counts, disp);
    gateup_kernel<<<dim3(CAP / BM, IDIM / BN, NEXP), 256, 0, stream>>>(disp, gp, up, hbuf);
    down_kernel<<<dim3(CAP / BM, DIM / BN, NEXP), 256, 0, stream>>>(hbuf, dp, eo);
    combine_kernel<<<NTOK, 256, 0, stream>>>(eo, top1, top2, slot1, slot2, w1, w2, out);
}

// Round 2
// 1342.883 us; speedup vs baseline: 1.1507x; 1.1507x over previous
//
#include <hip/hip_runtime.h>
#include <hip/hip_bf16.h>
#include <cstdint>
#include <cstddef>

// Problem constants (B,T,H,W,D)=(2,8,16,16,2048), E=16, I=2048
#define NTOK 4096   // N = B*T*H*W
#define NEXP 16     // E
#define DIM  2048   // D
#define IDIM 2048   // I
#define CAP  640    // 2 * ceil(N/E * 1.25)
#define SEQ  2048   // T*H*W
// token n <-> memory row (n&1)*SEQ + (n>>1)   (B=2)

typedef float v4f __attribute__((ext_vector_type(4)));
typedef short v8s __attribute__((ext_vector_type(8)));

__device__ __forceinline__ unsigned short f2b(float x) {
    union { float f; unsigned u; } c; c.f = x;
    unsigned r = c.u + 0x7FFFu + ((c.u >> 16) & 1u);
    return (unsigned short)(r >> 16);
}
__device__ __forceinline__ float b2f(unsigned short x) {
    union { unsigned u; float f; } c; c.u = ((unsigned)x) << 16;
    return c.f;
}

// async 16B global -> LDS (lds dest must be wave-uniform base; lane i lands at base + i*16B)
__device__ __forceinline__ void async16(const void* g, void* l) {
    __builtin_amdgcn_global_load_lds(
        (const __attribute__((address_space(1))) unsigned int*)g,
        (__attribute__((address_space(3))) unsigned int*)l,
        16, 0, 0);
}

// ---------------- Kernel 0: fp32 -> bf16 weight conversion ----------------
// exact cover: grid*256*8 == n
__global__ __launch_bounds__(256) void convert_kernel(
    const float* __restrict__ src, unsigned short* __restrict__ dst)
{
    size_t i = ((size_t)blockIdx.x * 256 + threadIdx.x) * 8;
    float4 a = *(const float4*)(src + i);
    float4 b = *(const float4*)(src + i + 4);
    v8s o;
    o[0]=(short)f2b(a.x); o[1]=(short)f2b(a.y); o[2]=(short)f2b(a.z); o[3]=(short)f2b(a.w);
    o[4]=(short)f2b(b.x); o[5]=(short)f2b(b.y); o[6]=(short)f2b(b.z); o[7]=(short)f2b(b.w);
    *(v8s*)(dst + i) = o;
}

// ---------------- Kernel 1: router (fp32 exact) ----------------
__global__ __launch_bounds__(256) void router_kernel(
    const float* __restrict__ hidden, const float* __restrict__ wg,
    int* __restrict__ top1, int* __restrict__ top2,
    float* __restrict__ w1, float* __restrict__ w2)
{
    int wid  = threadIdx.x >> 6;
    int lane = threadIdx.x & 63;
    int n = blockIdx.x * 4 + wid;
    int e = lane & 15;
    int chunk = lane >> 4;
    const float* tok  = hidden + ((size_t)(n & 1) * SEQ + (n >> 1)) * DIM;
    const float* wrow = wg + (size_t)e * DIM;
    float acc = 0.f;
    int d0 = chunk * (DIM / 4);
    #pragma unroll 4
    for (int d = d0; d < d0 + DIM / 4; d += 4) {
        float4 t4 = *(const float4*)(tok + d);
        float4 g4 = *(const float4*)(wrow + d);
        acc += t4.x * g4.x + t4.y * g4.y + t4.z * g4.z + t4.w * g4.w;
    }
    acc += __shfl_down(acc, 32);
    acc += __shfl_down(acc, 16);
    float v = acc;
    float v1 = v; int i1 = e;
    #pragma unroll
    for (int off = 8; off; off >>= 1) {
        float ov = __shfl_xor(v1, off);
        int   oi = __shfl_xor(i1, off);
        if (ov > v1 || (ov == v1 && oi < i1)) { v1 = ov; i1 = oi; }
    }
    float v2 = (e == i1) ? -INFINITY : v; int i2 = e;
    #pragma unroll
    for (int off = 8; off; off >>= 1) {
        float ov = __shfl_xor(v2, off);
        int   oi = __shfl_xor(i2, off);
        if (ov > v2 || (ov == v2 && oi < i2)) { v2 = ov; i2 = oi; }
    }
    if (lane == 0) {
        float e2v = expf(v2 - v1);
        float inv = 1.f / (1.f + e2v);
        top1[n] = i1; top2[n] = i2;
        w1[n] = inv;  w2[n] = e2v * inv;
    }
}

// ---------------- Kernel 2: slot scan (one wave per expert) ----------------
__global__ __launch_bounds__(1024) void slot_kernel(
    const int* __restrict__ top1, const int* __restrict__ top2,
    int* __restrict__ slot1, int* __restrict__ slot2,
    int* __restrict__ exp_tok, int* __restrict__ counts)
{
    int w = threadIdx.x >> 6;   // expert id
    int lane = threadIdx.x & 63;
    unsigned long long below = (lane == 0) ? 0ull : ((~0ull) >> (64 - lane));
    int base = 0;
    for (int c = 0; c < NTOK / 64; ++c) {
        int n = c * 64 + lane;
        bool p = (top1[n] == w);
        unsigned long long m = __ballot(p);
        if (p) {
            int s = base + __popcll(m & below);
            slot1[n] = s;
            if (s < CAP) exp_tok[w * CAP + s] = n;
        }
        base += __popcll(m);
    }
    for (int c = 0; c < NTOK / 64; ++c) {
        int n = c * 64 + lane;
        bool p = (top2[n] == w);
        unsigned long long m = __ballot(p);
        if (p) {
            int s = base + __popcll(m & below);
            slot2[n] = s;
            if (s < CAP) exp_tok[w * CAP + s] = n;
        }
        base += __popcll(m);
    }
    if (lane == 0) counts[w] = base < CAP ? base : CAP;
}

// ---------------- Kernel 3: dispatch/gather -> (E,C,D) bf16 ----------------
__global__ __launch_bounds__(256) void dispatch_kernel(
    const float* __restrict__ hidden, const int* __restrict__ exp_tok,
    const int* __restrict__ counts, unsigned short* __restrict__ disp)
{
    int s = blockIdx.x, e = blockIdx.y;
    unsigned short* dst = disp + ((size_t)e * CAP + s) * DIM + threadIdx.x * 8;
    if (s < counts[e]) {
        int n = exp_tok[e * CAP + s];
        const float* src = hidden + ((size_t)(n & 1) * SEQ + (n >> 1)) * DIM + threadIdx.x * 8;
        float4 a = *(const float4*)src;
        float4 b = *(const float4*)(src + 4);
        v8s o;
        o[0] = (short)f2b(a.x); o[1] = (short)f2b(a.y);
        o[2] = (short)f2b(a.z); o[3] = (short)f2b(a.w);
        o[4] = (short)f2b(b.x); o[5] = (short)f2b(b.y);
        o[6] = (short)f2b(b.z); o[7] = (short)f2b(b.w);
        *(v8s*)dst = o;
    } else {
        v8s z = {0, 0, 0, 0, 0, 0, 0, 0};
        *(v8s*)dst = z;
    }
}

// ---------------- GEMM tiling ----------------
// 128x128 tile, BK=64, all-bf16 operands, global_load_lds staging with
// XOR column-block swizzle: LDS slot (row, cb) holds global col-block cb^(row&7).
// Fragment b128 reads then hit 8 distinct bank-groups across lrow (2-way = free).
#define BM 128
#define BN 128
#define BK 64

// stage one 128x64 bf16 tile (row stride rs elems) into lds (128*64 shorts)
__device__ __forceinline__ void stage_tile(
    const unsigned short* __restrict__ gbase, int grow0, int k0, int rs,
    unsigned short* lds, int wv, int ln)
{
    int sr = ln >> 3;    // 0..7
    int cb = ln & 7;     // col-block
    #pragma unroll
    for (int p = 0; p < 4; ++p) {
        int r = p * 32 + wv * 8 + sr;
        const unsigned short* g = gbase + (size_t)(grow0 + r) * rs + k0 + ((cb ^ (r & 7)) << 3);
        async16(g, lds + (p * 32 + wv * 8) * 64);   // wave-uniform base
    }
}

// Kernel 4: h = silu(disp @ gpb^T) * (disp @ upb^T), per expert. Out bf16 (E,C,I)
__global__ __launch_bounds__(256) void gateup_kernel(
    const unsigned short* __restrict__ disp, const unsigned short* __restrict__ gpb,
    const unsigned short* __restrict__ upb, const int* __restrict__ counts,
    unsigned short* __restrict__ hbuf)
{
    __shared__ unsigned short As[BM * BK];
    __shared__ unsigned short Bgs[BN * BK];
    __shared__ unsigned short Bus[BN * BK];
    int e  = blockIdx.z;
    int m0 = blockIdx.x * BM;
    if (m0 >= counts[e]) return;   // rows beyond count never read by combine
    int n0 = blockIdx.y * BN;
    int tid = threadIdx.x;
    int wv = tid >> 6, ln = tid & 63;
    int wm = wv & 1, wn = wv >> 1;
    int lrow = ln & 15, quad = ln >> 4;
    int sw = lrow & 7;

    const unsigned short* Ab = disp + (size_t)e * CAP * DIM;
    const unsigned short* Gb = gpb + (size_t)e * IDIM * DIM;
    const unsigned short* Ub = upb + (size_t)e * IDIM * DIM;

    int arow[4], brow[4];
    #pragma unroll
    for (int i = 0; i < 4; ++i) {
        arow[i] = (wm * 64 + i * 16 + lrow) * 64;
        brow[i] = (wn * 64 + i * 16 + lrow) * 64;
    }

    v4f accg[4][4], accu[4][4];
    #pragma unroll
    for (int i = 0; i < 4; ++i)
        #pragma unroll
        for (int j = 0; j < 4; ++j) { accg[i][j] = (v4f)0.f; accu[i][j] = (v4f)0.f; }

    for (int k0 = 0; k0 < DIM; k0 += BK) {
        stage_tile(Ab, m0, k0, DIM, As, wv, ln);
        stage_tile(Gb, n0, k0, DIM, Bgs, wv, ln);
        stage_tile(Ub, n0, k0, DIM, Bus, wv, ln);
        __syncthreads();
        #pragma unroll
        for (int ks = 0; ks < BK; ks += 32) {
            int cq = ks >> 3;
            v8s a[4], bg[4], bu[4];
            #pragma unroll
            for (int i = 0; i < 4; ++i)
                a[i] = *(const v8s*)&As[arow[i] + (((cq + quad) ^ sw) << 3)];
            #pragma unroll
            for (int j = 0; j < 4; ++j) {
                bg[j] = *(const v8s*)&Bgs[brow[j] + (((cq + quad) ^ sw) << 3)];
                bu[j] = *(const v8s*)&Bus[brow[j] + (((cq + quad) ^ sw) << 3)];
            }
            #pragma unroll
            for (int i = 0; i < 4; ++i)
                #pragma unroll
                for (int j = 0; j < 4; ++j) {
                    accg[i][j] = __builtin_amdgcn_mfma_f32_16x16x32_bf16(a[i], bg[j], accg[i][j], 0, 0, 0);
                    accu[i][j] = __builtin_amdgcn_mfma_f32_16x16x32_bf16(a[i], bu[j], accu[i][j], 0, 0, 0);
                }
        }
        __syncthreads();
    }
    unsigned short* hb = hbuf + (size_t)e * CAP * IDIM;
    #pragma unroll
    for (int i = 0; i < 4; ++i)
        #pragma unroll
        for (int j = 0; j < 4; ++j) {
            int row = m0 + wm * 64 + i * 16 + quad * 4;
            int col = n0 + wn * 64 + j * 16 + lrow;
            #pragma unroll
            for (int rg = 0; rg < 4; ++rg) {
                float g = accg[i][j][rg], u = accu[i][j][rg];
                float hv = (g / (1.f + __expf(-g))) * u;
                hb[(size_t)(row + rg) * IDIM + col] = f2b(hv);
            }
        }
}

// Kernel 5: expert_out = h @ dpb^T per expert. Out bf16 (E,C,D)
__global__ __launch_bounds__(256) void down_kernel(
    const unsigned short* __restrict__ hbuf, const unsigned short* __restrict__ dpb,
    const int* __restrict__ counts, unsigned short* __restrict__ eo)
{
    __shared__ unsigned short As[BM * BK];
    __shared__ unsigned short Bs[BN * BK];
    int e  = blockIdx.z;
    int m0 = blockIdx.x * BM;
    if (m0 >= counts[e]) return;
    int n0 = blockIdx.y * BN;
    int tid = threadIdx.x;
    int wv = tid >> 6, ln = tid & 63;
    int wm = wv & 1, wn = wv >> 1;
    int lrow = ln & 15, quad = ln >> 4;
    int sw = lrow & 7;

    const unsigned short* Ab = hbuf + (size_t)e * CAP * IDIM;
    const unsigned short* Db = dpb + (size_t)e * DIM * IDIM;

    int arow[4], brow[4];
    #pragma unroll
    for (int i = 0; i < 4; ++i) {
        arow[i] = (wm * 64 + i * 16 + lrow) * 64;
        brow[i] = (wn * 64 + i * 16 + lrow) * 64;
    }

    v4f acc[4][4];
    #pragma unroll
    for (int i = 0; i < 4; ++i)
        #pragma unroll
        for (int j = 0; j < 4; ++j) acc[i][j] = (v4f)0.f;

    for (int k0 = 0; k0 < IDIM; k0 += BK) {
        stage_tile(Ab, m0, k0, IDIM, As, wv, ln);
        stage_tile(Db, n0, k0, IDIM, Bs, wv, ln);
        __syncthreads();
        #pragma unroll
        for (int ks = 0; ks < BK; ks += 32) {
            int cq = ks >> 3;
            v8s a[4], b[4];
            #pragma unroll
            for (int i = 0; i < 4; ++i)
                a[i] = *(const v8s*)&As[arow[i] + (((cq + quad) ^ sw) << 3)];
            #pragma unroll
            for (int j = 0; j < 4; ++j)
                b[j] = *(const v8s*)&Bs[brow[j] + (((cq + quad) ^ sw) << 3)];
            #pragma unroll
            for (int i = 0; i < 4; ++i)
                #pragma unroll
                for (int j = 0; j < 4; ++j)
                    acc[i][j] = __builtin_amdgcn_mfma_f32_16x16x32_bf16(a[i], b[j], acc[i][j], 0, 0, 0);
        }
        __syncthreads();
    }
    unsigned short* ob = eo + (size_t)e * CAP * DIM;
    #pragma unroll
    for (int i = 0; i < 4; ++i)
        #pragma unroll
        for (int j = 0; j < 4; ++j) {
            int row = m0 + wm * 64 + i * 16 + quad * 4;
            int col = n0 + wn * 64 + j * 16 + lrow;
            #pragma unroll
            for (int rg = 0; rg < 4; ++rg)
                ob[(size_t)(row + rg) * DIM + col] = f2b(acc[i][j][rg]);
        }
}

// ---------------- Kernel 6: combine ----------------
__global__ __launch_bounds__(256) void combine_kernel(
    const unsigned short* __restrict__ eo,
    const int* __restrict__ top1, const int* __restrict__ top2,
    const int* __restrict__ slot1, const int* __restrict__ slot2,
    const float* __restrict__ w1, const float* __restrict__ w2,
    float* __restrict__ out)
{
    int n = blockIdx.x;
    int d = threadIdx.x * 8;
    float acc[8];
    #pragma unroll
    for (int i = 0; i < 8; ++i) acc[i] = 0.f;
    int s1 = slot1[n], s2 = slot2[n];
    if (s1 < CAP) {
        const unsigned short* p = eo + ((size_t)top1[n] * CAP + s1) * DIM + d;
        float w = w1[n];
        v8s v = *(const v8s*)p;
        #pragma unroll
        for (int i = 0; i < 8; ++i) acc[i] += w * b2f((unsigned short)v[i]);
    }
    if (s2 < CAP) {
        const unsigned short* p = eo + ((size_t)top2[n] * CAP + s2) * DIM + d;
        float w = w2[n];
        v8s v = *(const v8s*)p;
        #pragma unroll
        for (int i = 0; i < 8; ++i) acc[i] += w * b2f((unsigned short)v[i]);
    }
    float* o = out + ((size_t)(n & 1) * SEQ + (n >> 1)) * DIM + d;
    float4 o0 = {acc[0], acc[1], acc[2], acc[3]};
    float4 o1 = {acc[4], acc[5], acc[6], acc[7]};
    *(float4*)o = o0;
    *(float4*)(o + 4) = o1;
}

extern "C" void kernel_launch(void* const* d_in, const int* in_sizes, int n_in,
                              void* d_out, int out_size, void* d_ws, size_t ws_size,
                              hipStream_t stream) {
    const float* hidden = (const float*)d_in[0];
    const float* wg     = (const float*)d_in[1];
    const float* gp     = (const float*)d_in[2];
    const float* up     = (const float*)d_in[3];
    const float* dp     = (const float*)d_in[4];
    float* out = (float*)d_out;
    char* ws = (char*)d_ws;

    // workspace layout
    int*   top1    = (int*)(ws + 0);
    int*   top2    = (int*)(ws + 16384);
    float* w1      = (float*)(ws + 32768);
    float* w2      = (float*)(ws + 49152);
    int*   slot1   = (int*)(ws + 65536);
    int*   slot2   = (int*)(ws + 81920);
    int*   counts  = (int*)(ws + 98304);
    int*   exp_tok = (int*)(ws + 98560);
    unsigned short* disp = (unsigned short*)(ws + 262144);                    // 41,943,040 B
    unsigned short* hbuf = (unsigned short*)(ws + 262144 + 41943040ull);      // 41,943,040 B
    unsigned short* eo   = (unsigned short*)(ws + 262144 + 2ull*41943040ull); // 41,943,040 B
    unsigned short* W1   = (unsigned short*)(ws + 262144 + 3ull*41943040ull); // 134,217,728 B (gpb, then dpb)
    unsigned short* W2   = (unsigned short*)(ws + 262144 + 3ull*41943040ull + 134217728ull); // upb
    // total ~394.5 MB

    const int WBLK = (NEXP * IDIM * DIM) / 2048;  // 32768 blocks, exact cover

    router_kernel<<<NTOK / 4, 256, 0, stream>>>(hidden, wg, top1, top2, w1, w2);
    slot_kernel<<<1, 1024, 0, stream>>>(top1, top2, slot1, slot2, exp_tok, counts);
    dispatch_kernel<<<dim3(CAP, NEXP), 256, 0, stream>>>(hidden, exp_tok, counts, disp);
    convert_kernel<<<WBLK, 256, 0, stream>>>(gp, W1);
    convert_kernel<<<WBLK, 256, 0, stream>>>(up, W2);
    gateup_kernel<<<dim3(CAP / BM, IDIM / BN, NEXP), 256, 0, stream>>>(disp, W1, W2, counts, hbuf);
    convert_kernel<<<WBLK, 256, 0, stream>>>(dp, W1);   // dpb aliases gpb region
    down_kernel<<<dim3(CAP / BM, DIM / BN, NEXP), 256, 0, stream>>>(hbuf, W1, counts, eo);
    combine_kernel<<<NTOK, 256, 0, stream>>>(eo, top1, top2, slot1, slot2, w1, w2, out);
}